// Round 8
// baseline (130.326 us; speedup 1.0000x reference)
//
#include <hip/hip_runtime.h>

#define NBATCH 4096
#define SEQ 512
#define HID 5
#define NEMB 64

__device__ __forceinline__ float fexp2(float x){ return __builtin_amdgcn_exp2f(x); }
__device__ __forceinline__ float frcp(float x){ return __builtin_amdgcn_rcpf(x); }

// ds_swizzle BitMode: offset=(xor<<10)|(or<<5)|(and); and=0, or=4k -> all lanes read lane 4k of their 32-half
#define SWZ(v, k) __int_as_float(__builtin_amdgcn_ds_swizzle(__float_as_int(v), ((4*(k)) << 5)))
// quad_perm broadcast of quad-lane j to the whole quad
#define DPPQ(v, j) __int_as_float(__builtin_amdgcn_update_dpp(0, __float_as_int(v), ((j) * 0x55), 0xF, 0xF, true))

__global__ __launch_bounds__(64) void lstm_enc_kernel(
    const float* __restrict__ x_num, const int* __restrict__ x_cat,
    const float* __restrict__ embed, const float* __restrict__ W_ih,
    const float* __restrict__ W_hh, const float* __restrict__ b_ih,
    const float* __restrict__ b_hh, float* __restrict__ out)
{
    __shared__ float4 s_emb[NEMB];
    int tid = threadIdx.x;
    s_emb[tid] = ((const float4*)embed)[tid];
    __syncthreads();

    // one wave = 4 batch elements: 2 spatial halves x 2 temporal streams (A,B).
    // within a half: lane l -> unit k=min(l>>2,4), gate g=l&3. quads 5..7 duplicate unit 4.
    int half = tid >> 5;
    int l    = tid & 31;
    int bA   = blockIdx.x * 4 + half;
    int bB   = bA + 2;
    int k    = ((l >> 2) < HID) ? (l >> 2) : (HID - 1);
    int g    = l & 3;                       // 0:i 1:f 2:g 3:o
    bool st  = (l < 20) && (g == 0);        // h_k holder lanes: 0,4,8,12,16

    const float L2E = 1.4426950408889634f;
    float s_  = (g == 2) ? (-2.0f * L2E) : (-L2E);   // prescale (tanh gate: 2sigma-1 form)
    float fm  = (g == 2) ? 2.0f : 1.0f;
    float fb  = (g == 2) ? -1.0f : 0.0f;

    int row = g * HID + k;
    float wi_[5], wh_[5];
#pragma unroll
    for (int d = 0; d < 5; ++d) {
        wi_[d] = W_ih[row * 5 + d] * s_;
        wh_[d] = W_hh[row * 5 + d] * s_;
    }
    float bias = (b_ih[row] + b_hh[row]) * s_;

    const float4* xpA = (const float4*)(x_num + (size_t)bA * SEQ);
    const int4*   cpA = (const int4*)(x_cat + (size_t)bA * SEQ);
    float* outpA = out + (size_t)bA * SEQ * HID + k;
    const float4* xpB = (const float4*)(x_num + (size_t)bB * SEQ);
    const int4*   cpB = (const int4*)(x_cat + (size_t)bB * SEQ);
    float* outpB = out + (size_t)bB * SEQ * HID + k;

    float hA = 0.f, cA = 0.f, hB = 0.f, cB = 0.f;
    float hbA0 = 0.f, hbA1 = 0.f, hbA2 = 0.f, hbA3 = 0.f, hbA4 = 0.f;
    float hbB0 = 0.f, hbB1 = 0.f, hbB2 = 0.f, hbB3 = 0.f, hbB4 = 0.f;

    float4 xfA = xpA[0];  int4 cfA = cpA[0];
    float4 xfB = xpB[0];  int4 cfB = cpB[0];
    float4 ecA_[4], ecB_[4];
    ecA_[0] = s_emb[cfA.x]; ecA_[1] = s_emb[cfA.y]; ecA_[2] = s_emb[cfA.z]; ecA_[3] = s_emb[cfA.w];
    ecB_[0] = s_emb[cfB.x]; ecB_[1] = s_emb[cfB.y]; ecB_[2] = s_emb[cfB.z]; ecB_[3] = s_emb[cfB.w];

    for (int t0 = 0; t0 < SEQ; t0 += 4) {
        int nidx = (t0 + 4 < SEQ) ? ((t0 >> 2) + 1) : 0;
        float4 xfA_n = xpA[nidx];  int4 cfA_n = cpA[nidx];
        float4 xfB_n = xpB[nidx];  int4 cfB_n = cpB[nidx];

        float xnA[4] = {xfA.x, xfA.y, xfA.z, xfA.w};
        float xnB[4] = {xfB.x, xfB.y, xfB.z, xfB.w};

        // off-chain: bias + x + emb part for both streams, all 4 steps
        float xaA[4], xaB[4];
#pragma unroll
        for (int u = 0; u < 4; ++u) {
            float4 eA = ecA_[u];
            float a = fmaf(xnA[u], wi_[0], bias);
            a = fmaf(eA.x, wi_[1], a);
            a = fmaf(eA.y, wi_[2], a);
            a = fmaf(eA.z, wi_[3], a);
            a = fmaf(eA.w, wi_[4], a);
            xaA[u] = a;
            float4 eB = ecB_[u];
            float bx = fmaf(xnB[u], wi_[0], bias);
            bx = fmaf(eB.x, wi_[1], bx);
            bx = fmaf(eB.y, wi_[2], bx);
            bx = fmaf(eB.z, wi_[3], bx);
            bx = fmaf(eB.w, wi_[4], bx);
            xaB[u] = bx;
        }

#pragma unroll
        for (int u = 0; u < 4; ++u) {
            // ---- stream A (its swizzles from previous segment have had B's segment to land) ----
            {
                float a = xaA[u];
                a = fmaf(hbA0, wh_[0], a);
                a = fmaf(hbA1, wh_[1], a);
                a = fmaf(hbA2, wh_[2], a);
                a = fmaf(hbA3, wh_[3], a);
                a = fmaf(hbA4, wh_[4], a);
                float r = frcp(1.0f + fexp2(a));
                float v = fmaf(r, fm, fb);
                float ai = DPPQ(v, 0);
                float af = DPPQ(v, 1);
                float ag = DPPQ(v, 2);
                float ao = DPPQ(v, 3);
                cA = fmaf(af, cA, ai * ag);
                float tc = fmaf(frcp(1.0f + fexp2(cA * (-2.0f * L2E))), 2.0f, -1.0f);
                hA = ao * tc;
                hbA0 = SWZ(hA, 0);
                hbA1 = SWZ(hA, 1);
                hbA2 = SWZ(hA, 2);
                hbA3 = SWZ(hA, 3);
                hbA4 = SWZ(hA, 4);
                if (st) outpA[(t0 + u) * HID] = hA;
            }
            // ---- stream B (covers A's swizzle latency) ----
            {
                float a = xaB[u];
                a = fmaf(hbB0, wh_[0], a);
                a = fmaf(hbB1, wh_[1], a);
                a = fmaf(hbB2, wh_[2], a);
                a = fmaf(hbB3, wh_[3], a);
                a = fmaf(hbB4, wh_[4], a);
                float r = frcp(1.0f + fexp2(a));
                float v = fmaf(r, fm, fb);
                float ai = DPPQ(v, 0);
                float af = DPPQ(v, 1);
                float ag = DPPQ(v, 2);
                float ao = DPPQ(v, 3);
                cB = fmaf(af, cB, ai * ag);
                float tc = fmaf(frcp(1.0f + fexp2(cB * (-2.0f * L2E))), 2.0f, -1.0f);
                hB = ao * tc;
                hbB0 = SWZ(hB, 0);
                hbB1 = SWZ(hB, 1);
                hbB2 = SWZ(hB, 2);
                hbB3 = SWZ(hB, 3);
                hbB4 = SWZ(hB, 4);
                if (st) outpB[(t0 + u) * HID] = hB;
            }
        }

        ecA_[0] = s_emb[cfA_n.x]; ecA_[1] = s_emb[cfA_n.y]; ecA_[2] = s_emb[cfA_n.z]; ecA_[3] = s_emb[cfA_n.w];
        ecB_[0] = s_emb[cfB_n.x]; ecB_[1] = s_emb[cfB_n.y]; ecB_[2] = s_emb[cfB_n.z]; ecB_[3] = s_emb[cfB_n.w];
        xfA = xfA_n; xfB = xfB_n;
    }

    if (st) {
        size_t base = (size_t)NBATCH * SEQ * HID;
        out[base + (size_t)bA * HID + k] = hA;
        out[base + (size_t)NBATCH * HID + (size_t)bA * HID + k] = cA;
        out[base + (size_t)bB * HID + k] = hB;
        out[base + (size_t)NBATCH * HID + (size_t)bB * HID + k] = cB;
    }
}

extern "C" void kernel_launch(void* const* d_in, const int* in_sizes, int n_in,
                              void* d_out, int out_size, void* d_ws, size_t ws_size,
                              hipStream_t stream) {
    const float* x_num = (const float*)d_in[0];
    const int*   x_cat = (const int*)d_in[1];
    const float* embed = (const float*)d_in[2];
    const float* W_ih  = (const float*)d_in[3];
    const float* W_hh  = (const float*)d_in[4];
    const float* b_ih  = (const float*)d_in[5];
    const float* b_hh  = (const float*)d_in[6];
    float* out = (float*)d_out;

    dim3 grid(NBATCH / 4);   // 1024 blocks, 1 wave each: 4 elements/wave (2 spatial x 2 temporal)
    dim3 block(64);
    hipLaunchKernelGGL(lstm_enc_kernel, grid, block, 0, stream,
                       x_num, x_cat, embed, W_ih, W_hh, b_ih, b_hh, out);
}